// Round 1
// baseline (875.371 us; speedup 1.0000x reference)
//
#include <hip/hip_runtime.h>
#include <math.h>

// LogEntmaxBisect: out = log(entmax_bisect(X, alpha=1.5)) row-wise over last dim.
// For alpha=1.5, p(z)=relu(z)^2 and the bisection converges to the exact tau
// solving sum_{supp}(Xs - tau)^2 = 1, a quadratic in tau given support stats.
// We compute tau by iterative support refinement (2 iterations when support is
// dense, as the data guarantees), keeping the whole row in registers so HBM
// traffic is read-once + write-once (memory-bound floor ~166 us).

constexpr int D     = 32000;          // row length
constexpr int BLOCK = 640;            // 10 waves
constexpr int NW    = BLOCK / 64;     // 10
constexpr int VPT   = D / BLOCK;      // 50 floats per thread
constexpr int V2    = VPT / 2;        // 25 float2 per thread

__global__ __launch_bounds__(BLOCK) void
log_entmax_kernel(const float* __restrict__ X, float* __restrict__ out) {
    const int row  = blockIdx.x;
    const int tid  = threadIdx.x;
    const int lane = tid & 63;
    const int wave = tid >> 6;

    __shared__ float red[NW][4];      // [wave][{k, s1, q, -}]

    const float2* __restrict__ src = reinterpret_cast<const float2*>(X + (size_t)row * D);
    float2* __restrict__       dst = reinterpret_cast<float2*>(out + (size_t)row * D);

    // Load row into registers; Xs = 0.5 * X  (alpha-1 = 0.5)
    float xs[VPT];
#pragma unroll
    for (int j = 0; j < V2; ++j) {
        float2 v = src[j * BLOCK + tid];
        xs[2 * j]     = 0.5f * v.x;
        xs[2 * j + 1] = 0.5f * v.y;
    }

    // Iterative support refinement for tau (block-uniform, no divergence):
    //   support = {i : Xs_i > tau}; tau = mu - sqrt(mu^2 - (Q-1)/k)
    // Starting from tau = -inf (full support). Dense support -> converges in
    // 2 iterations (second reproduces identical stats -> tnew == tau -> break).
    float tau = -INFINITY;
    for (int it = 0; it < 16; ++it) {
        float k = 0.f, s1 = 0.f, q = 0.f;
#pragma unroll
        for (int j = 0; j < VPT; ++j) {
            float v = xs[j];
            if (v > tau) { k += 1.f; s1 += v; q += v * v; }
        }
#pragma unroll
        for (int o = 32; o > 0; o >>= 1) {
            k  += __shfl_down(k, o);
            s1 += __shfl_down(s1, o);
            q  += __shfl_down(q, o);
        }
        if (lane == 0) { red[wave][0] = k; red[wave][1] = s1; red[wave][2] = q; }
        __syncthreads();
        k = 0.f; s1 = 0.f; q = 0.f;
#pragma unroll
        for (int w = 0; w < NW; ++w) {
            k += red[w][0]; s1 += red[w][1]; q += red[w][2];
        }
        __syncthreads();  // red reused next iteration

        float mu   = s1 / k;
        float disc = mu * mu - (q - 1.0f) / k;
        float tnew = mu - sqrtf(fmaxf(disc, 0.0f));
        if (tnew == tau) break;   // uniform: all threads compute identical value
        tau = tnew;
    }

    // Normalization sum S = sum relu(Xs - tau)^2 (fp32, like the reference's renorm)
    float S = 0.f;
#pragma unroll
    for (int j = 0; j < VPT; ++j) {
        float z = fmaxf(xs[j] - tau, 0.f);
        S += z * z;
    }
#pragma unroll
    for (int o = 32; o > 0; o >>= 1) S += __shfl_down(S, o);
    if (lane == 0) red[wave][0] = S;
    __syncthreads();
    S = 0.f;
#pragma unroll
    for (int w = 0; w < NW; ++w) S += red[w][0];

    const float lS = __logf(S);

    // out = log(p) = 2*log(relu(Xs - tau)) - log(S)
#pragma unroll
    for (int j = 0; j < V2; ++j) {
        float z0 = fmaxf(xs[2 * j]     - tau, 0.f);
        float z1 = fmaxf(xs[2 * j + 1] - tau, 0.f);
        float2 o;
        o.x = 2.f * __logf(z0) - lS;
        o.y = 2.f * __logf(z1) - lS;
        dst[j * BLOCK + tid] = o;
    }
}

extern "C" void kernel_launch(void* const* d_in, const int* in_sizes, int n_in,
                              void* d_out, int out_size, void* d_ws, size_t ws_size,
                              hipStream_t stream) {
    const float* X = (const float*)d_in[0];
    float* out     = (float*)d_out;
    const int rows = in_sizes[0] / D;   // 4096
    log_entmax_kernel<<<rows, BLOCK, 0, stream>>>(X, out);
}